// Round 1
// baseline (364.332 us; speedup 1.0000x reference)
//
#include <hip/hip_runtime.h>
#include <hip/hip_bf16.h>
#include <math.h>

#define N_ 8192
#define A_ 512
#define D_ 512
#define NN_ 3

// ---------------------------------------------------------------------------
// Kernel 1: per-anchor 3-NN + Cayley-Menger determinant quality.
// One block (256 threads) per anchor.
// ---------------------------------------------------------------------------
__global__ __launch_bounds__(256) void anchor_cm_kernel(
    const float* __restrict__ anchors, float* __restrict__ quality) {
  __shared__ float ai[D_];       // anchor i vector
  __shared__ float dist[A_];     // distances to all anchors
  __shared__ float red[256];
  __shared__ int   redi[256];
  __shared__ float gram_s[10];
  __shared__ float sqi_s;

  const int i = blockIdx.x;
  const int t = threadIdx.x;

  // stage anchor i into LDS
  for (int d = t; d < D_; d += 256) ai[d] = anchors[i * D_ + d];
  __syncthreads();

  // sq_i = dot(a_i, a_i) via block reduce
  {
    float p = 0.f;
    for (int d = t; d < D_; d += 256) p += ai[d] * ai[d];
    red[t] = p;
    __syncthreads();
    for (int s = 128; s > 0; s >>= 1) {
      if (t < s) red[t] += red[t + s];
      __syncthreads();
    }
    if (t == 0) sqi_s = red[0];
    __syncthreads();
  }
  const float sqi = sqi_s;

  // distances to every anchor j (reference: sqrt(max(sqi+sqj-2*dot,0)) + eye*1e12)
  for (int j = t; j < A_; j += 256) {
    const float* aj = anchors + (size_t)j * D_;
    float dot = 0.f, sqj = 0.f;
    for (int d = 0; d < D_; d += 4) {
      float4 v = *reinterpret_cast<const float4*>(aj + d);
      dot += ai[d + 0] * v.x + ai[d + 1] * v.y + ai[d + 2] * v.z + ai[d + 3] * v.w;
      sqj += v.x * v.x + v.y * v.y + v.z * v.z + v.w * v.w;
    }
    float d2 = fmaxf(sqi + sqj - 2.f * dot, 0.f);
    float dd = sqrtf(d2);
    if (j == i) dd += 1e12f;
    dist[j] = dd;
  }
  __syncthreads();

  // 3x argmin with (value, index) lexicographic tie-break (stable argsort)
  int nn[NN_];
  for (int r = 0; r < NN_; ++r) {
    float best = 1e30f;
    int bi = 0x7fffffff;
    for (int j = t; j < A_; j += 256) {
      float v = dist[j];
      if (v < best || (v == best && j < bi)) { best = v; bi = j; }
    }
    red[t] = best; redi[t] = bi;
    __syncthreads();
    for (int s = 128; s > 0; s >>= 1) {
      if (t < s) {
        float ov = red[t + s]; int oi = redi[t + s];
        if (ov < red[t] || (ov == red[t] && oi < redi[t])) { red[t] = ov; redi[t] = oi; }
      }
      __syncthreads();
    }
    int w = redi[0];            // all threads read winner
    nn[r] = w;
    __syncthreads();
    if (t == 0) dist[w] = 1e30f;  // exclude for next round
    __syncthreads();
  }

  // 10 unique gram entries among {i, nn0, nn1, nn2}
  const int i1 = nn[0], i2 = nn[1], i3 = nn[2];
  float part[10];
#pragma unroll
  for (int p = 0; p < 10; ++p) part[p] = 0.f;
  for (int d = t; d < D_; d += 256) {
    float v0 = ai[d];
    float v1 = anchors[(size_t)i1 * D_ + d];
    float v2 = anchors[(size_t)i2 * D_ + d];
    float v3 = anchors[(size_t)i3 * D_ + d];
    part[0] += v0 * v0; part[1] += v0 * v1; part[2] += v0 * v2; part[3] += v0 * v3;
    part[4] += v1 * v1; part[5] += v1 * v2; part[6] += v1 * v3;
    part[7] += v2 * v2; part[8] += v2 * v3;
    part[9] += v3 * v3;
  }
  for (int p = 0; p < 10; ++p) {
    red[t] = part[p];
    __syncthreads();
    for (int s = 128; s > 0; s >>= 1) {
      if (t < s) red[t] += red[t + s];
      __syncthreads();
    }
    if (t == 0) gram_s[p] = red[0];
    __syncthreads();
  }

  if (t == 0) {
    // unpack 4x4 gram
    float G[4][4];
    G[0][0] = gram_s[0]; G[0][1] = gram_s[1]; G[0][2] = gram_s[2]; G[0][3] = gram_s[3];
    G[1][1] = gram_s[4]; G[1][2] = gram_s[5]; G[1][3] = gram_s[6];
    G[2][2] = gram_s[7]; G[2][3] = gram_s[8];
    G[3][3] = gram_s[9];
    G[1][0] = G[0][1]; G[2][0] = G[0][2]; G[3][0] = G[0][3];
    G[2][1] = G[1][2]; G[3][1] = G[1][3]; G[3][2] = G[2][3];

    // Cayley-Menger 5x5 matrix in double
    double M[5][5];
    M[0][0] = 0.0;
    for (int q = 1; q < 5; ++q) { M[0][q] = 1.0; M[q][0] = 1.0; }
    for (int p = 0; p < 4; ++p)
      for (int q = 0; q < 4; ++q) {
        // reference computes d2 in f32: diag_p + diag_q - 2*G[p][q]
        float d2f = G[p][p] + G[q][q] - 2.f * G[p][q];
        M[p + 1][q + 1] = (double)d2f;
      }

    // det via partial-pivot Gaussian elimination (double)
    double det = 1.0;
    for (int c = 0; c < 5; ++c) {
      int piv = c;
      double mx = fabs(M[c][c]);
      for (int r2 = c + 1; r2 < 5; ++r2) {
        double v = fabs(M[r2][c]);
        if (v > mx) { mx = v; piv = r2; }
      }
      if (piv != c) {
        for (int c2 = 0; c2 < 5; ++c2) { double tmp = M[c][c2]; M[c][c2] = M[piv][c2]; M[piv][c2] = tmp; }
        det = -det;
      }
      double pv = M[c][c];
      det *= pv;
      if (pv == 0.0) break;
      for (int r2 = c + 1; r2 < 5; ++r2) {
        double f = M[r2][c] / pv;
        for (int c2 = c; c2 < 5; ++c2) M[r2][c2] -= f * M[c][c2];
      }
    }
    // sign_corr = (-1)^K, K=4 -> +1
    float raw = (float)det;
    float sg = (raw > 0.f) ? 1.f : ((raw < 0.f) ? -1.f : 0.f);
    quality[i] = sg * logf(fabsf(raw) + 1e-12f);
  }
}

// ---------------------------------------------------------------------------
// Kernel 2: normalize quality -> (q - mean) / max(std_ddof1, 1e-8). 1 block.
// ---------------------------------------------------------------------------
__global__ __launch_bounds__(A_) void norm_cm_kernel(
    const float* __restrict__ quality, float* __restrict__ cmn) {
  __shared__ float red[A_];
  const int t = threadIdx.x;
  float q = quality[t];
  red[t] = q;
  __syncthreads();
  for (int s = A_ / 2; s > 0; s >>= 1) {
    if (t < s) red[t] += red[t + s];
    __syncthreads();
  }
  float mean = red[0] * (1.0f / A_);
  __syncthreads();
  float dq = q - mean;
  red[t] = dq * dq;
  __syncthreads();
  for (int s = A_ / 2; s > 0; s >>= 1) {
    if (t < s) red[t] += red[t + s];
    __syncthreads();
  }
  float sd = sqrtf(red[0] * (1.0f / (A_ - 1)));
  sd = fmaxf(sd, 1e-8f);
  cmn[t] = dq / sd;
}

// ---------------------------------------------------------------------------
// Kernel 3: fused stable-rank + gate MLP + sigmoid. One block per row of tri.
// ---------------------------------------------------------------------------
__global__ __launch_bounds__(A_) void gate_kernel(
    const float* __restrict__ tri, const float* __restrict__ cmn,
    const float* __restrict__ W1, const float* __restrict__ b1,
    const float* __restrict__ W2, const float* __restrict__ b2,
    float* __restrict__ out) {
  __shared__ float row[A_];
  const int n = blockIdx.x;
  const int t = threadIdx.x;

  const float ti = tri[(size_t)n * A_ + t];
  row[t] = ti;
  __syncthreads();

  // stable rank: #(v<ti) + #(v==ti && j<t)  == argsort(argsort(tri))
  int cnt = 0;
  const float4* row4 = reinterpret_cast<const float4*>(row);
#pragma unroll 8
  for (int j4 = 0; j4 < A_ / 4; ++j4) {
    float4 v = row4[j4];
    int j = j4 * 4;
    cnt += (v.x < ti) || (v.x == ti && (j + 0) < t);
    cnt += (v.y < ti) || (v.y == ti && (j + 1) < t);
    cnt += (v.z < ti) || (v.z == ti && (j + 2) < t);
    cnt += (v.w < ti) || (v.w == ti && (j + 3) < t);
  }
  const float rank = (float)cnt * (1.0f / (A_ - 1));

  const float f0 = cmn[t];
  const float f1 = 1.0f - ti;

  float logit = b2[0];
#pragma unroll
  for (int k = 0; k < 16; ++k) {
    float x = W1[k * 3 + 0] * f0 + W1[k * 3 + 1] * f1 + W1[k * 3 + 2] * rank + b1[k];
    // exact GELU: 0.5*x*(1+erf(x/sqrt(2)))
    float g = 0.5f * x * (1.0f + erff(x * 0.70710678118654752440f));
    logit += W2[k] * g;
  }
  out[(size_t)n * A_ + t] = 1.0f / (1.0f + expf(-logit));
}

// ---------------------------------------------------------------------------
extern "C" void kernel_launch(void* const* d_in, const int* in_sizes, int n_in,
                              void* d_out, int out_size, void* d_ws, size_t ws_size,
                              hipStream_t stream) {
  // inputs: 0 embedding (unused), 1 anchors, 2 tri, 3 W1, 4 b1, 5 W2, 6 b2
  const float* anchors = (const float*)d_in[1];
  const float* tri     = (const float*)d_in[2];
  const float* W1      = (const float*)d_in[3];
  const float* b1      = (const float*)d_in[4];
  const float* W2      = (const float*)d_in[5];
  const float* b2      = (const float*)d_in[6];
  float* out = (float*)d_out;

  float* quality = (float*)d_ws;              // A_ floats
  float* cmn     = quality + A_;              // A_ floats

  anchor_cm_kernel<<<A_, 256, 0, stream>>>(anchors, quality);
  norm_cm_kernel<<<1, A_, 0, stream>>>(quality, cmn);
  gate_kernel<<<N_, A_, 0, stream>>>(tri, cmn, W1, b1, W2, b2, out);
}

// Round 2
// 235.812 us; speedup vs baseline: 1.5450x; 1.5450x over previous
//
#include <hip/hip_runtime.h>
#include <hip/hip_bf16.h>
#include <math.h>

#define N_ 8192
#define A_ 512
#define D_ 512
#define NN_ 3

// ---------------------------------------------------------------------------
// Kernel 1: per-anchor 3-NN + Cayley-Menger determinant quality.
// One block (256 threads) per anchor.  (unchanged from passing round)
// ---------------------------------------------------------------------------
__global__ __launch_bounds__(256) void anchor_cm_kernel(
    const float* __restrict__ anchors, float* __restrict__ quality) {
  __shared__ float ai[D_];       // anchor i vector
  __shared__ float dist[A_];     // distances to all anchors
  __shared__ float red[256];
  __shared__ int   redi[256];
  __shared__ float gram_s[10];
  __shared__ float sqi_s;

  const int i = blockIdx.x;
  const int t = threadIdx.x;

  for (int d = t; d < D_; d += 256) ai[d] = anchors[i * D_ + d];
  __syncthreads();

  {
    float p = 0.f;
    for (int d = t; d < D_; d += 256) p += ai[d] * ai[d];
    red[t] = p;
    __syncthreads();
    for (int s = 128; s > 0; s >>= 1) {
      if (t < s) red[t] += red[t + s];
      __syncthreads();
    }
    if (t == 0) sqi_s = red[0];
    __syncthreads();
  }
  const float sqi = sqi_s;

  for (int j = t; j < A_; j += 256) {
    const float* aj = anchors + (size_t)j * D_;
    float dot = 0.f, sqj = 0.f;
    for (int d = 0; d < D_; d += 4) {
      float4 v = *reinterpret_cast<const float4*>(aj + d);
      dot += ai[d + 0] * v.x + ai[d + 1] * v.y + ai[d + 2] * v.z + ai[d + 3] * v.w;
      sqj += v.x * v.x + v.y * v.y + v.z * v.z + v.w * v.w;
    }
    float d2 = fmaxf(sqi + sqj - 2.f * dot, 0.f);
    float dd = sqrtf(d2);
    if (j == i) dd += 1e12f;
    dist[j] = dd;
  }
  __syncthreads();

  int nn[NN_];
  for (int r = 0; r < NN_; ++r) {
    float best = 1e30f;
    int bi = 0x7fffffff;
    for (int j = t; j < A_; j += 256) {
      float v = dist[j];
      if (v < best || (v == best && j < bi)) { best = v; bi = j; }
    }
    red[t] = best; redi[t] = bi;
    __syncthreads();
    for (int s = 128; s > 0; s >>= 1) {
      if (t < s) {
        float ov = red[t + s]; int oi = redi[t + s];
        if (ov < red[t] || (ov == red[t] && oi < redi[t])) { red[t] = ov; redi[t] = oi; }
      }
      __syncthreads();
    }
    int w = redi[0];
    nn[r] = w;
    __syncthreads();
    if (t == 0) dist[w] = 1e30f;
    __syncthreads();
  }

  const int i1 = nn[0], i2 = nn[1], i3 = nn[2];
  float part[10];
#pragma unroll
  for (int p = 0; p < 10; ++p) part[p] = 0.f;
  for (int d = t; d < D_; d += 256) {
    float v0 = ai[d];
    float v1 = anchors[(size_t)i1 * D_ + d];
    float v2 = anchors[(size_t)i2 * D_ + d];
    float v3 = anchors[(size_t)i3 * D_ + d];
    part[0] += v0 * v0; part[1] += v0 * v1; part[2] += v0 * v2; part[3] += v0 * v3;
    part[4] += v1 * v1; part[5] += v1 * v2; part[6] += v1 * v3;
    part[7] += v2 * v2; part[8] += v2 * v3;
    part[9] += v3 * v3;
  }
  for (int p = 0; p < 10; ++p) {
    red[t] = part[p];
    __syncthreads();
    for (int s = 128; s > 0; s >>= 1) {
      if (t < s) red[t] += red[t + s];
      __syncthreads();
    }
    if (t == 0) gram_s[p] = red[0];
    __syncthreads();
  }

  if (t == 0) {
    float G[4][4];
    G[0][0] = gram_s[0]; G[0][1] = gram_s[1]; G[0][2] = gram_s[2]; G[0][3] = gram_s[3];
    G[1][1] = gram_s[4]; G[1][2] = gram_s[5]; G[1][3] = gram_s[6];
    G[2][2] = gram_s[7]; G[2][3] = gram_s[8];
    G[3][3] = gram_s[9];
    G[1][0] = G[0][1]; G[2][0] = G[0][2]; G[3][0] = G[0][3];
    G[2][1] = G[1][2]; G[3][1] = G[1][3]; G[3][2] = G[2][3];

    double M[5][5];
    M[0][0] = 0.0;
    for (int q = 1; q < 5; ++q) { M[0][q] = 1.0; M[q][0] = 1.0; }
    for (int p = 0; p < 4; ++p)
      for (int q = 0; q < 4; ++q) {
        float d2f = G[p][p] + G[q][q] - 2.f * G[p][q];
        M[p + 1][q + 1] = (double)d2f;
      }

    double det = 1.0;
    for (int c = 0; c < 5; ++c) {
      int piv = c;
      double mx = fabs(M[c][c]);
      for (int r2 = c + 1; r2 < 5; ++r2) {
        double v = fabs(M[r2][c]);
        if (v > mx) { mx = v; piv = r2; }
      }
      if (piv != c) {
        for (int c2 = 0; c2 < 5; ++c2) { double tmp = M[c][c2]; M[c][c2] = M[piv][c2]; M[piv][c2] = tmp; }
        det = -det;
      }
      double pv = M[c][c];
      det *= pv;
      if (pv == 0.0) break;
      for (int r2 = c + 1; r2 < 5; ++r2) {
        double f = M[r2][c] / pv;
        for (int c2 = c; c2 < 5; ++c2) M[r2][c2] -= f * M[c][c2];
      }
    }
    float raw = (float)det;
    float sg = (raw > 0.f) ? 1.f : ((raw < 0.f) ? -1.f : 0.f);
    quality[i] = sg * logf(fabsf(raw) + 1e-12f);
  }
}

// ---------------------------------------------------------------------------
// Kernel 2: normalize quality -> (q - mean) / max(std_ddof1, 1e-8). 1 block.
// ---------------------------------------------------------------------------
__global__ __launch_bounds__(A_) void norm_cm_kernel(
    const float* __restrict__ quality, float* __restrict__ cmn) {
  __shared__ float red[A_];
  const int t = threadIdx.x;
  float q = quality[t];
  red[t] = q;
  __syncthreads();
  for (int s = A_ / 2; s > 0; s >>= 1) {
    if (t < s) red[t] += red[t + s];
    __syncthreads();
  }
  float mean = red[0] * (1.0f / A_);
  __syncthreads();
  float dq = q - mean;
  red[t] = dq * dq;
  __syncthreads();
  for (int s = A_ / 2; s > 0; s >>= 1) {
    if (t < s) red[t] += red[t + s];
    __syncthreads();
  }
  float sd = sqrtf(red[0] * (1.0f / (A_ - 1)));
  sd = fmaxf(sd, 1e-8f);
  cmn[t] = dq / sd;
}

// ---------------------------------------------------------------------------
// Kernel 3a: build 64-bit stable-rank keys: ((u64)float_bits << 9) | col.
// tri values are in [0,2) (nonnegative) so IEEE bit pattern is order-monotone.
// Stable rank of element i == #(key_j < key_i), exactly (integer compare).
// ---------------------------------------------------------------------------
__global__ __launch_bounds__(256) void key_build_kernel(
    const float* __restrict__ tri, unsigned long long* __restrict__ keys) {
  const int idx4 = (blockIdx.x * 256 + threadIdx.x) * 4;
  float4 v = *reinterpret_cast<const float4*>(tri + idx4);
  const unsigned col = (unsigned)(idx4 & (A_ - 1));
  ulonglong2 k01, k23;
  k01.x = ((unsigned long long)__float_as_uint(v.x) << 9) | (col + 0);
  k01.y = ((unsigned long long)__float_as_uint(v.y) << 9) | (col + 1);
  k23.x = ((unsigned long long)__float_as_uint(v.z) << 9) | (col + 2);
  k23.y = ((unsigned long long)__float_as_uint(v.w) << 9) | (col + 3);
  *reinterpret_cast<ulonglong2*>(keys + idx4)     = k01;
  *reinterpret_cast<ulonglong2*>(keys + idx4 + 2) = k23;
}

// ---------------------------------------------------------------------------
// Kernel 3b: fused rank + gate MLP + sigmoid. One block (512 thr) per row.
// Row keys are block-uniform -> compiler emits SCALAR loads (s_load, K$,
// SALU pipe) so the VALU loop is just v_cmp_lt_u64 + addc per element.
// ---------------------------------------------------------------------------
__global__ __launch_bounds__(A_) void gate_kernel_smem(
    const unsigned long long* __restrict__ keys,
    const float* __restrict__ cmn,
    const float* __restrict__ W1, const float* __restrict__ b1,
    const float* __restrict__ W2, const float* __restrict__ b2,
    float* __restrict__ out) {
  const int n = blockIdx.x;
  const int t = threadIdx.x;
  const unsigned long long* krow = keys + (size_t)n * A_;
  const unsigned long long ki = krow[t];

  int cnt = 0;
  const ulonglong2* krow2 = reinterpret_cast<const ulonglong2*>(krow);
#pragma unroll 16
  for (int j2 = 0; j2 < A_ / 2; ++j2) {
    ulonglong2 kk = krow2[j2];   // uniform address -> s_load
    cnt += (kk.x < ki);
    cnt += (kk.y < ki);
  }
  const float rank = (float)cnt * (1.0f / (A_ - 1));

  const float ti = __uint_as_float((unsigned)(ki >> 9));
  const float f0 = cmn[t];
  const float f1 = 1.0f - ti;

  float logit = b2[0];
#pragma unroll
  for (int k = 0; k < 16; ++k) {
    float x = W1[k * 3 + 0] * f0 + W1[k * 3 + 1] * f1 + W1[k * 3 + 2] * rank + b1[k];
    float g = 0.5f * x * (1.0f + erff(x * 0.70710678118654752440f));
    logit += W2[k] * g;
  }
  out[(size_t)n * A_ + t] = 1.0f / (1.0f + expf(-logit));
}

// ---------------------------------------------------------------------------
// Kernel 3 fallback (ws too small for keys): LDS float4 path (round-1 code).
// ---------------------------------------------------------------------------
__global__ __launch_bounds__(A_) void gate_kernel_lds(
    const float* __restrict__ tri, const float* __restrict__ cmn,
    const float* __restrict__ W1, const float* __restrict__ b1,
    const float* __restrict__ W2, const float* __restrict__ b2,
    float* __restrict__ out) {
  __shared__ float row[A_];
  const int n = blockIdx.x;
  const int t = threadIdx.x;

  const float ti = tri[(size_t)n * A_ + t];
  row[t] = ti;
  __syncthreads();

  int cnt = 0;
  const float4* row4 = reinterpret_cast<const float4*>(row);
#pragma unroll 8
  for (int j4 = 0; j4 < A_ / 4; ++j4) {
    float4 v = row4[j4];
    int j = j4 * 4;
    cnt += (v.x < ti) || (v.x == ti && (j + 0) < t);
    cnt += (v.y < ti) || (v.y == ti && (j + 1) < t);
    cnt += (v.z < ti) || (v.z == ti && (j + 2) < t);
    cnt += (v.w < ti) || (v.w == ti && (j + 3) < t);
  }
  const float rank = (float)cnt * (1.0f / (A_ - 1));

  const float f0 = cmn[t];
  const float f1 = 1.0f - ti;

  float logit = b2[0];
#pragma unroll
  for (int k = 0; k < 16; ++k) {
    float x = W1[k * 3 + 0] * f0 + W1[k * 3 + 1] * f1 + W1[k * 3 + 2] * rank + b1[k];
    float g = 0.5f * x * (1.0f + erff(x * 0.70710678118654752440f));
    logit += W2[k] * g;
  }
  out[(size_t)n * A_ + t] = 1.0f / (1.0f + expf(-logit));
}

// ---------------------------------------------------------------------------
extern "C" void kernel_launch(void* const* d_in, const int* in_sizes, int n_in,
                              void* d_out, int out_size, void* d_ws, size_t ws_size,
                              hipStream_t stream) {
  // inputs: 0 embedding (unused), 1 anchors, 2 tri, 3 W1, 4 b1, 5 W2, 6 b2
  const float* anchors = (const float*)d_in[1];
  const float* tri     = (const float*)d_in[2];
  const float* W1      = (const float*)d_in[3];
  const float* b1      = (const float*)d_in[4];
  const float* W2      = (const float*)d_in[5];
  const float* b2      = (const float*)d_in[6];
  float* out = (float*)d_out;

  const size_t keybytes = (size_t)N_ * A_ * sizeof(unsigned long long);  // 32 MB
  const bool use_keys = ws_size >= keybytes + 4096;

  if (use_keys) {
    unsigned long long* keys = (unsigned long long*)d_ws;
    float* quality = (float*)((char*)d_ws + keybytes);   // A_ floats
    float* cmn     = quality + A_;                       // A_ floats

    anchor_cm_kernel<<<A_, 256, 0, stream>>>(anchors, quality);
    key_build_kernel<<<(N_ * A_) / (4 * 256), 256, 0, stream>>>(tri, keys);
    norm_cm_kernel<<<1, A_, 0, stream>>>(quality, cmn);
    gate_kernel_smem<<<N_, A_, 0, stream>>>(keys, cmn, W1, b1, W2, b2, out);
  } else {
    float* quality = (float*)d_ws;
    float* cmn     = quality + A_;
    anchor_cm_kernel<<<A_, 256, 0, stream>>>(anchors, quality);
    norm_cm_kernel<<<1, A_, 0, stream>>>(quality, cmn);
    gate_kernel_lds<<<N_, A_, 0, stream>>>(tri, cmn, W1, b1, W2, b2, out);
  }
}

// Round 3
// 126.297 us; speedup vs baseline: 2.8847x; 1.8671x over previous
//
#include <hip/hip_runtime.h>
#include <hip/hip_bf16.h>
#include <math.h>

#define N_ 8192
#define A_ 512
#define D_ 512
#define NN_ 3

// ---------------------------------------------------------------------------
// Kernel 1: per-anchor 3-NN + Cayley-Menger determinant quality.
// One block (256 threads) per anchor.  (unchanged from passing round)
// ---------------------------------------------------------------------------
__global__ __launch_bounds__(256) void anchor_cm_kernel(
    const float* __restrict__ anchors, float* __restrict__ quality) {
  __shared__ float ai[D_];       // anchor i vector
  __shared__ float dist[A_];     // distances to all anchors
  __shared__ float red[256];
  __shared__ int   redi[256];
  __shared__ float gram_s[10];
  __shared__ float sqi_s;

  const int i = blockIdx.x;
  const int t = threadIdx.x;

  for (int d = t; d < D_; d += 256) ai[d] = anchors[i * D_ + d];
  __syncthreads();

  {
    float p = 0.f;
    for (int d = t; d < D_; d += 256) p += ai[d] * ai[d];
    red[t] = p;
    __syncthreads();
    for (int s = 128; s > 0; s >>= 1) {
      if (t < s) red[t] += red[t + s];
      __syncthreads();
    }
    if (t == 0) sqi_s = red[0];
    __syncthreads();
  }
  const float sqi = sqi_s;

  for (int j = t; j < A_; j += 256) {
    const float* aj = anchors + (size_t)j * D_;
    float dot = 0.f, sqj = 0.f;
    for (int d = 0; d < D_; d += 4) {
      float4 v = *reinterpret_cast<const float4*>(aj + d);
      dot += ai[d + 0] * v.x + ai[d + 1] * v.y + ai[d + 2] * v.z + ai[d + 3] * v.w;
      sqj += v.x * v.x + v.y * v.y + v.z * v.z + v.w * v.w;
    }
    float d2 = fmaxf(sqi + sqj - 2.f * dot, 0.f);
    float dd = sqrtf(d2);
    if (j == i) dd += 1e12f;
    dist[j] = dd;
  }
  __syncthreads();

  int nn[NN_];
  for (int r = 0; r < NN_; ++r) {
    float best = 1e30f;
    int bi = 0x7fffffff;
    for (int j = t; j < A_; j += 256) {
      float v = dist[j];
      if (v < best || (v == best && j < bi)) { best = v; bi = j; }
    }
    red[t] = best; redi[t] = bi;
    __syncthreads();
    for (int s = 128; s > 0; s >>= 1) {
      if (t < s) {
        float ov = red[t + s]; int oi = redi[t + s];
        if (ov < red[t] || (ov == red[t] && oi < redi[t])) { red[t] = ov; redi[t] = oi; }
      }
      __syncthreads();
    }
    int w = redi[0];
    nn[r] = w;
    __syncthreads();
    if (t == 0) dist[w] = 1e30f;
    __syncthreads();
  }

  const int i1 = nn[0], i2 = nn[1], i3 = nn[2];
  float part[10];
#pragma unroll
  for (int p = 0; p < 10; ++p) part[p] = 0.f;
  for (int d = t; d < D_; d += 256) {
    float v0 = ai[d];
    float v1 = anchors[(size_t)i1 * D_ + d];
    float v2 = anchors[(size_t)i2 * D_ + d];
    float v3 = anchors[(size_t)i3 * D_ + d];
    part[0] += v0 * v0; part[1] += v0 * v1; part[2] += v0 * v2; part[3] += v0 * v3;
    part[4] += v1 * v1; part[5] += v1 * v2; part[6] += v1 * v3;
    part[7] += v2 * v2; part[8] += v2 * v3;
    part[9] += v3 * v3;
  }
  for (int p = 0; p < 10; ++p) {
    red[t] = part[p];
    __syncthreads();
    for (int s = 128; s > 0; s >>= 1) {
      if (t < s) red[t] += red[t + s];
      __syncthreads();
    }
    if (t == 0) gram_s[p] = red[0];
    __syncthreads();
  }

  if (t == 0) {
    float G[4][4];
    G[0][0] = gram_s[0]; G[0][1] = gram_s[1]; G[0][2] = gram_s[2]; G[0][3] = gram_s[3];
    G[1][1] = gram_s[4]; G[1][2] = gram_s[5]; G[1][3] = gram_s[6];
    G[2][2] = gram_s[7]; G[2][3] = gram_s[8];
    G[3][3] = gram_s[9];
    G[1][0] = G[0][1]; G[2][0] = G[0][2]; G[3][0] = G[0][3];
    G[2][1] = G[1][2]; G[3][1] = G[1][3]; G[3][2] = G[2][3];

    double M[5][5];
    M[0][0] = 0.0;
    for (int q = 1; q < 5; ++q) { M[0][q] = 1.0; M[q][0] = 1.0; }
    for (int p = 0; p < 4; ++p)
      for (int q = 0; q < 4; ++q) {
        float d2f = G[p][p] + G[q][q] - 2.f * G[p][q];
        M[p + 1][q + 1] = (double)d2f;
      }

    double det = 1.0;
    for (int c = 0; c < 5; ++c) {
      int piv = c;
      double mx = fabs(M[c][c]);
      for (int r2 = c + 1; r2 < 5; ++r2) {
        double v = fabs(M[r2][c]);
        if (v > mx) { mx = v; piv = r2; }
      }
      if (piv != c) {
        for (int c2 = 0; c2 < 5; ++c2) { double tmp = M[c][c2]; M[c][c2] = M[piv][c2]; M[piv][c2] = tmp; }
        det = -det;
      }
      double pv = M[c][c];
      det *= pv;
      if (pv == 0.0) break;
      for (int r2 = c + 1; r2 < 5; ++r2) {
        double f = M[r2][c] / pv;
        for (int c2 = c; c2 < 5; ++c2) M[r2][c2] -= f * M[c][c2];
      }
    }
    float raw = (float)det;
    float sg = (raw > 0.f) ? 1.f : ((raw < 0.f) ? -1.f : 0.f);
    quality[i] = sg * logf(fabsf(raw) + 1e-12f);
  }
}

// ---------------------------------------------------------------------------
// Kernel 2: normalize quality -> (q - mean) / max(std_ddof1, 1e-8). 1 block.
// ---------------------------------------------------------------------------
__global__ __launch_bounds__(A_) void norm_cm_kernel(
    const float* __restrict__ quality, float* __restrict__ cmn) {
  __shared__ float red[A_];
  const int t = threadIdx.x;
  float q = quality[t];
  red[t] = q;
  __syncthreads();
  for (int s = A_ / 2; s > 0; s >>= 1) {
    if (t < s) red[t] += red[t + s];
    __syncthreads();
  }
  float mean = red[0] * (1.0f / A_);
  __syncthreads();
  float dq = q - mean;
  red[t] = dq * dq;
  __syncthreads();
  for (int s = A_ / 2; s > 0; s >>= 1) {
    if (t < s) red[t] += red[t + s];
    __syncthreads();
  }
  float sd = sqrtf(red[0] * (1.0f / (A_ - 1)));
  sd = fmaxf(sd, 1e-8f);
  cmn[t] = dq / sd;
}

// ---------------------------------------------------------------------------
// Kernel 3: bucket-histogram stable rank + gate MLP + sigmoid.
// One block (512 thr) per row. tri values are uniform in [0,2):
//   bucket b = trunc(ti*128) in [0,255] is monotone non-decreasing in value,
//   so rank = #(buckets<b) + #(key< key_i within bucket b), exactly.
// u64 key = (float_bits << 9) | col reproduces the stable argsort tie-break.
// ---------------------------------------------------------------------------
__global__ __launch_bounds__(A_) void gate_kernel_bucket(
    const float* __restrict__ tri, const float* __restrict__ cmn,
    const float* __restrict__ W1, const float* __restrict__ b1,
    const float* __restrict__ W2, const float* __restrict__ b2,
    float* __restrict__ out) {
  __shared__ int hist[256];
  __shared__ int pref[256];     // exclusive prefix per bucket
  __shared__ int cursor[256];
  __shared__ unsigned long long sorted[A_];

  const int n = blockIdx.x;
  const int t = threadIdx.x;

  const float ti = tri[(size_t)n * A_ + t];
  const unsigned long long key =
      ((unsigned long long)__float_as_uint(ti) << 9) | (unsigned)t;
  int b = (int)(ti * 128.0f);
  b = (b < 0) ? 0 : ((b > 255) ? 255 : b);

  if (t < 256) { hist[t] = 0; cursor[t] = 0; }
  __syncthreads();
  atomicAdd(&hist[b], 1);
  __syncthreads();

  // exclusive prefix over 256 buckets: wave 0, 4 buckets per lane + shfl scan
  if (t < 64) {
    const int b4 = t * 4;
    int h0 = hist[b4 + 0], h1 = hist[b4 + 1], h2 = hist[b4 + 2], h3 = hist[b4 + 3];
    int s = h0 + h1 + h2 + h3;
    int incl = s;
#pragma unroll
    for (int d = 1; d < 64; d <<= 1) {
      int u = __shfl_up(incl, d);
      if (t >= d) incl += u;
    }
    int ex = incl - s;
    pref[b4 + 0] = ex;
    pref[b4 + 1] = ex + h0;
    pref[b4 + 2] = ex + h0 + h1;
    pref[b4 + 3] = ex + h0 + h1 + h2;
  }
  __syncthreads();

  // scatter key into its bucket segment (order within bucket irrelevant)
  const int pos = pref[b] + atomicAdd(&cursor[b], 1);
  sorted[pos] = key;
  __syncthreads();

  // rank = prefix(bucket) + stable count within bucket
  const int start = pref[b];
  const int len = hist[b];
  int cnt = start;
  for (int m = 0; m < len; ++m) cnt += (sorted[start + m] < key);
  const float rank = (float)cnt * (1.0f / (A_ - 1));

  const float f0 = cmn[t];
  const float f1 = 1.0f - ti;

  float logit = b2[0];
#pragma unroll
  for (int k = 0; k < 16; ++k) {
    float x = W1[k * 3 + 0] * f0 + W1[k * 3 + 1] * f1 + W1[k * 3 + 2] * rank + b1[k];
    float g = 0.5f * x * (1.0f + erff(x * 0.70710678118654752440f));
    logit += W2[k] * g;
  }
  out[(size_t)n * A_ + t] = 1.0f / (1.0f + expf(-logit));
}

// ---------------------------------------------------------------------------
extern "C" void kernel_launch(void* const* d_in, const int* in_sizes, int n_in,
                              void* d_out, int out_size, void* d_ws, size_t ws_size,
                              hipStream_t stream) {
  // inputs: 0 embedding (unused), 1 anchors, 2 tri, 3 W1, 4 b1, 5 W2, 6 b2
  const float* anchors = (const float*)d_in[1];
  const float* tri     = (const float*)d_in[2];
  const float* W1      = (const float*)d_in[3];
  const float* b1      = (const float*)d_in[4];
  const float* W2      = (const float*)d_in[5];
  const float* b2      = (const float*)d_in[6];
  float* out = (float*)d_out;

  float* quality = (float*)d_ws;              // A_ floats
  float* cmn     = quality + A_;              // A_ floats

  anchor_cm_kernel<<<A_, 256, 0, stream>>>(anchors, quality);
  norm_cm_kernel<<<1, A_, 0, stream>>>(quality, cmn);
  gate_kernel_bucket<<<N_, A_, 0, stream>>>(tri, cmn, W1, b1, W2, b2, out);
}